// Round 14
// baseline (76.271 us; speedup 1.0000x reference)
//
#include <hip/hip_runtime.h>

typedef __bf16 bf16;
typedef __attribute__((ext_vector_type(4))) __bf16 bf16x4;
typedef __attribute__((ext_vector_type(8))) __bf16 bf16x8;
typedef __attribute__((ext_vector_type(4))) float f32x4;
typedef unsigned int u32;

#define MFMA16(a, b, c) __builtin_amdgcn_mfma_f32_16x16x32_bf16((a), (b), (c), 0, 0, 0)
#define LOG2E 1.4426950408889634f
#define AS1 __attribute__((address_space(1)))
#define AS3 __attribute__((address_space(3)))
#define GLL16(g, l) __builtin_amdgcn_global_load_lds((const AS1 u32*)(g), (AS3 u32*)(l), 16, 0, 0)

// KV chunk, per (b, kt=0..7): 81920 bytes =
//  [0,16384):     K tile [128 q][64 o] bf16, identity rows, 16B-blk swz ^(q&7)
//  [16384,81920): V packed for DIRECT wave-fragment loads: octet (c, mm)
//     (mm = kv>>3 within chunk) at byte 16384 + (c>>6)<<14 + (mm>>2)<<12 +
//     ((c>>4)&3)<<10 + (mm&3)<<8 + (c&15)<<4.  attn wave w: load k=4kb+ct at
//     (w<<14)+(k<<10)+(lane<<4) == A-frag (c=64w+16ct+l16, octet mm=4kb+u).

// ---------------------------------------------------------------------------
// Kernel 1: fused V-pack + W prep (unchanged from R12).
// ---------------------------------------------------------------------------
__global__ __launch_bounds__(256) void vprep_kernel(const float* __restrict__ kf,
                                                    const float* __restrict__ Wq,
                                                    const float* __restrict__ Wk,
                                                    const int* __restrict__ flag,
                                                    bf16* __restrict__ KV,
                                                    bf16* __restrict__ Wbh,
                                                    bf16* __restrict__ Wbl) {
  const int bid = blockIdx.x, t = threadIdx.x;
  if (bid < 4096) {
    int i = (bid << 8) + t;  // (b, c, q8)
    int q8 = i & 127, c = (i >> 7) & 255, b = i >> 15;
    const float* src = kf + ((size_t)(((b << 8) + c)) << 10) + (q8 << 3);
    float4 f0 = *(const float4*)src;
    float4 f1 = *(const float4*)(src + 4);
    bf16x8 v;
    v[0] = (bf16)f0.x; v[1] = (bf16)f0.y; v[2] = (bf16)f0.z; v[3] = (bf16)f0.w;
    v[4] = (bf16)f1.x; v[5] = (bf16)f1.y; v[6] = (bf16)f1.z; v[7] = (bf16)f1.w;
    int kt = q8 >> 4, mm = q8 & 15;
    char* dst = (char*)KV + (size_t)((b << 3) + kt) * 81920 + 16384 +
                ((c >> 6) << 14) + ((mm >> 2) << 12) + (((c >> 4) & 3) << 10) +
                ((mm & 3) << 8) + ((c & 15) << 4);
    *(bf16x8*)dst = v;
  } else {
    int bx = bid - 4096;  // 0..31
    int z = bx >> 4;
    const float* src = (z == 0) ? Wq : ((flag[0] != 0) ? Wq : Wk);
    const float sc = (z == 0) ? LOG2E : 1.0f;  // exp2-domain softmax
    int i = ((((bx & 15) << 8) + t) << 2);
    float4 vv = *(const float4*)(src + i);
    vv.x *= sc; vv.y *= sc; vv.z *= sc; vv.w *= sc;
    bf16x4 hi, lo;
    hi[0] = (bf16)vv.x; lo[0] = (bf16)(vv.x - (float)hi[0]);
    hi[1] = (bf16)vv.y; lo[1] = (bf16)(vv.y - (float)hi[1]);
    hi[2] = (bf16)vv.z; lo[2] = (bf16)(vv.z - (float)hi[2]);
    hi[3] = (bf16)vv.w; lo[3] = (bf16)(vv.w - (float)hi[3]);
    *(bf16x4*)(Wbh + (z << 14) + i) = hi;
    *(bf16x4*)(Wbl + (z << 14) + i) = lo;
  }
}

// ---------------------------------------------------------------------------
// Kernel 2: K-projection only (Q moved into attn). grid (8, 32) x 256 thr.
// B-frags read bf16 from packed KV V-region; K stored identity-rows + swz.
// ---------------------------------------------------------------------------
__global__ __launch_bounds__(256) void proj_kernel(const bf16* __restrict__ Wbh,
                                                   const bf16* __restrict__ Wbl,
                                                   const float* __restrict__ bq,
                                                   const float* __restrict__ bk,
                                                   const int* __restrict__ flag,
                                                   bf16* __restrict__ KV) {
  const int b = blockIdx.y;
  const bf16* Wh = Wbh + 16384;
  const bf16* Wl = Wbl + 16384;
  const float* bias = flag[0] ? bq : bk;

  const int t = threadIdx.x;
  const int w = t >> 6, lane = t & 63;
  const int g = lane >> 4, l16 = lane & 15;
  const int wo = w >> 1, wp = w & 1;
  const int o0 = wo << 5;
  const int pbase = (blockIdx.x << 7) + (wp << 6);

  f32x4 acc[2][4];
#pragma unroll
  for (int ot = 0; ot < 2; ++ot) {
    float4 bv = *(const float4*)(bias + o0 + (ot << 4) + (g << 2));
#pragma unroll
    for (int pt = 0; pt < 4; ++pt) acc[ot][pt] = (f32x4){bv.x, bv.y, bv.z, bv.w};
  }

  const bf16* whb = Wh + ((o0 + l16) << 8) + (g << 3);
  const bf16* wlb = Wl + ((o0 + l16) << 8) + (g << 3);

  for (int kk = 0; kk < 8; ++kk) {
    bf16x8 ah[2], al[2];
#pragma unroll
    for (int ot = 0; ot < 2; ++ot) {
      ah[ot] = *(const bf16x8*)(whb + (ot << 12) + (kk << 5));
      al[ot] = *(const bf16x8*)(wlb + (ot << 12) + (kk << 5));
    }
#pragma unroll
    for (int pt = 0; pt < 4; ++pt) {
      // c = kk*32+8g+j ; p = pbase+16pt+l16 ; kt = p>>7
      const int p = pbase + (pt << 4) + l16;
      const int mm = (p & 127) >> 3, e = p & 7;
      const char* vp = (const char*)KV + (size_t)((b << 3) + (p >> 7)) * 81920 +
                       16384 + ((kk >> 1) << 14) + ((mm >> 2) << 12) +
                       ((((kk & 1) << 1) + (g >> 1)) << 10) + ((mm & 3) << 8) +
                       (((g & 1) << 3) << 4) + (e << 1);
      bf16x8 xf;
#pragma unroll
      for (int j = 0; j < 8; ++j) xf[j] = *(const bf16*)(vp + (j << 4));
#pragma unroll
      for (int ot = 0; ot < 2; ++ot) {
        acc[ot][pt] = MFMA16(ah[ot], xf, acc[ot][pt]);
        acc[ot][pt] = MFMA16(al[ot], xf, acc[ot][pt]);
      }
    }
  }

#pragma unroll
  for (int ot = 0; ot < 2; ++ot)
#pragma unroll
    for (int pt = 0; pt < 4; ++pt) {
      bf16x4 q4;
#pragma unroll
      for (int r = 0; r < 4; ++r) q4[r] = (bf16)acc[ot][pt][r];
      int p = pbase + (pt << 4) + l16;
      int kt = p >> 7, q = p & 127;
      int blk = (o0 >> 3) + (ot << 1) + (g >> 1);
      char* dst = (char*)KV + (size_t)((b << 3) + kt) * 81920 + q * 128 +
                  16 * (blk ^ (q & 7)) + ((g & 1) << 3);
      *(bf16x4*)dst = q4;
    }
}

// ---------------------------------------------------------------------------
// Kernel 3: fused Q-proj + flash attention. grid 512 (XCD-swz) x 256 thr.
// Prologue: K0 gll issued, then wave w computes Q[16px x 64o] (W hi/lo MFMA,
// qf fp32) -> sQ (8KB, K-image layout); each wave re-reads ONLY its own rows
// (no cross-wave race; sQ disjoint from sP). Main loop = R12 (KVBLK=128,
// no-max exp2 softmax, V global->VGPR packed frags, P via sP, 2 barriers/it).
// ---------------------------------------------------------------------------
__global__ __launch_bounds__(256, 2) void attn_kernel(const bf16* __restrict__ KV,
                                                      const float* __restrict__ qf,
                                                      const bf16* __restrict__ Wbh,
                                                      const bf16* __restrict__ Wbl,
                                                      const float* __restrict__ bq,
                                                      float* __restrict__ out) {
  const int bid = blockIdx.x;
  const int wkid = ((bid & 7) << 6) + (bid >> 3);  // bijective: 512 % 8 == 0
  const int b = wkid >> 4, ptile = wkid & 15;
  const int p0 = ptile << 6;
  const int t = threadIdx.x;
  const int w = t >> 6, lane = t & 63;
  const int u = lane >> 4, l16 = lane & 15;

  __shared__ __align__(16) unsigned char sK[2][16384];  // K dbuf (gll target)
  __shared__ __align__(16) unsigned char sP[16384];     // [64 px][128 kv], swz
  __shared__ __align__(16) unsigned char sQ[8192];      // [64 px][64 o], swz
  __shared__ float sL[64];

  const char* chunk0 = (const char*)KV + (size_t)b * (8 * 81920);
  const int prow = (w << 4) + l16, pswz = prow & 7;

  // ---- issue K_0 gll early (latency hides under Q-projection) ----
  {
    const char* g = chunk0 + (w << 12) + (lane << 4);
    unsigned char* l = sK[0] + (w << 12);
#pragma unroll
    for (int op = 0; op < 4; ++op) GLL16(g + op * 1024, l + op * 1024);
  }

  // ---- Q-projection: Q[px=prow][o=0..64), W hi/lo, fp32 acc ----
  {
    f32x4 qacc[4];
#pragma unroll
    for (int ot = 0; ot < 4; ++ot) {
      float4 bv = *(const float4*)(bq + (ot << 4) + (u << 2));
      qacc[ot] = (f32x4){bv.x * LOG2E, bv.y * LOG2E, bv.z * LOG2E, bv.w * LOG2E};
    }
    const float* xqb = qf + ((size_t)b << 18) + p0 + (w << 4) + l16;
    const bf16* whb = Wbh + (l16 << 8) + (u << 3);  // z=0 region (log2e-scaled)
    const bf16* wlb = Wbl + (l16 << 8) + (u << 3);
    for (int kk = 0; kk < 8; ++kk) {
      float xv[8];
#pragma unroll
      for (int j = 0; j < 8; ++j) xv[j] = xqb[(size_t)((kk << 5) + (u << 3) + j) << 10];
      bf16x8 xf;
#pragma unroll
      for (int j = 0; j < 8; ++j) xf[j] = (bf16)xv[j];
#pragma unroll
      for (int ot = 0; ot < 4; ++ot) {
        bf16x8 ah = *(const bf16x8*)(whb + (ot << 12) + (kk << 5));
        bf16x8 al = *(const bf16x8*)(wlb + (ot << 12) + (kk << 5));
        qacc[ot] = MFMA16(ah, xf, qacc[ot]);
        qacc[ot] = MFMA16(al, xf, qacc[ot]);
      }
    }
    // publish D (col px = l16, rows o = 16ot+4u+r) into sQ row prow
#pragma unroll
    for (int ot = 0; ot < 4; ++ot) {
      bf16x4 q4;
#pragma unroll
      for (int r = 0; r < 4; ++r) q4[r] = (bf16)qacc[ot][r];
      int blk = (ot << 1) + (u >> 1);
      *(bf16x4*)(sQ + prow * 128 + 16 * (blk ^ pswz) + ((u & 1) << 3)) = q4;
    }
  }
  asm volatile("s_waitcnt vmcnt(0)" ::: "memory");
  __syncthreads();  // K_0 landed; sQ rows visible (read-by-writer-wave only)

  // Q B-fragments for this wave's 16 px (col=px, k=o) from own sQ rows
  const bf16x8 qa0 = *(const bf16x8*)(sQ + prow * 128 + 16 * (u ^ pswz));
  const bf16x8 qa1 = *(const bf16x8*)(sQ + prow * 128 + 16 * ((u + 4) ^ pswz));

  f32x4 acc[4][4];  // [pg][ct]: c = 64w + 16ct + 4u + r ; px = 16pg + l16
#pragma unroll
  for (int i = 0; i < 4; ++i)
#pragma unroll
    for (int j = 0; j < 4; ++j) acc[i][j] = (f32x4){0.f, 0.f, 0.f, 0.f};
  float l_ = 0.f;

  const int Rb = ((l16 >> 2) << 3) + ((l16 & 3) << 1);  // K row perm base

  int cur = 0;
  for (int kt = 0; kt < 8; ++kt) {
    // ---- V_t -> regs: 16 coalesced 1KB loads (packed A-fragments) ----
    bf16x8 vr[16];  // vr[4kb+ct] = V A-frag (c=64w+16ct+l16, octet 4kb+u)
    const char* vsrc = chunk0 + kt * 81920 + 16384 + (w << 14) + (lane << 4);
#pragma unroll
    for (int k = 0; k < 16; ++k) vr[k] = *(const bf16x8*)(vsrc + (k << 10));
    // ---- K_{t+1} gll into other buffer ----
    if (kt < 7) {
      const char* g = chunk0 + (kt + 1) * 81920 + (w << 12) + (lane << 4);
      unsigned char* l = sK[cur ^ 1] + (w << 12);
#pragma unroll
      for (int op = 0; op < 4; ++op) GLL16(g + op * 1024, l + op * 1024);
    }
    const unsigned char* sKc = sK[cur];

    // ---- S^T = K·Q^T (16 mfma, permuted K rows from swizzled LDS) ----
    f32x4 s[8];
#pragma unroll
    for (int qt = 0; qt < 8; ++qt) {
      const int R = Rb + (qt & 1) + ((qt >> 1) << 5);
      const int rb = R * 128;
      bf16x8 k0 = *(const bf16x8*)(sKc + rb + 16 * (u ^ (R & 7)));
      bf16x8 k1 = *(const bf16x8*)(sKc + rb + 16 * ((u + 4) ^ (R & 7)));
      f32x4 z = (f32x4){0.f, 0.f, 0.f, 0.f};
      z = MFMA16(k0, qa0, z);
      s[qt] = MFMA16(k1, qa1, z);
    }
    // ---- NO-MAX softmax: P = exp2(S); l += sum ----
#pragma unroll
    for (int qt = 0; qt < 8; ++qt)
#pragma unroll
      for (int r = 0; r < 4; ++r) s[qt][r] = exp2f(s[qt][r]);
    float rs = 0.f;
#pragma unroll
    for (int qt = 0; qt < 8; ++qt)
      rs += (s[qt][0] + s[qt][1]) + (s[qt][2] + s[qt][3]);
    rs += __shfl_xor(rs, 16);
    rs += __shfl_xor(rs, 32);
    l_ += rs;
    // ---- P -> bf16 octets (in-lane), publish 4 b128 ----
#pragma unroll
    for (int a = 0; a < 4; ++a) {
      bf16x8 pb;
#pragma unroll
      for (int r = 0; r < 4; ++r) {
        pb[2 * r] = (bf16)s[2 * a][r];
        pb[2 * r + 1] = (bf16)s[2 * a + 1][r];
      }
      *(bf16x8*)(sP + prow * 256 + 16 * (((a << 2) + u) ^ pswz)) = pb;
    }
    __syncthreads();  // (1) P visible

    // ---- PV: 4 kb-groups x [4 P-frag reads + 16 mfma] ----
#pragma unroll
    for (int kb = 0; kb < 4; ++kb) {
      bf16x8 pbr[4];
#pragma unroll
      for (int pg = 0; pg < 4; ++pg) {
        const int rr = (pg << 4) + l16;
        pbr[pg] = *(const bf16x8*)(sP + rr * 256 + 16 * (((kb << 2) + u) ^ (rr & 7)));
      }
#pragma unroll
      for (int ct = 0; ct < 4; ++ct)
#pragma unroll
        for (int pg = 0; pg < 4; ++pg)
          acc[pg][ct] = MFMA16(vr[(kb << 2) + ct], pbr[pg], acc[pg][ct]);
    }
    asm volatile("s_waitcnt vmcnt(0)" ::: "memory");
    __syncthreads();  // (2) K_{t+1} landed; sP/sK reads done
    cur ^= 1;
  }

  // ---- epilogue: share l, per-lane normalize, direct stores ----
  if (lane < 16) sL[(w << 4) + lane] = l_;
  __syncthreads();
#pragma unroll
  for (int pg = 0; pg < 4; ++pg) {
    const float inv = 1.f / sL[(pg << 4) + l16];
    float* ob = out + ((size_t)b << 18) + p0 + (pg << 4) + l16;
#pragma unroll
    for (int ct = 0; ct < 4; ++ct)
#pragma unroll
      for (int r = 0; r < 4; ++r) {
        int c = (w << 6) + (ct << 4) + (u << 2) + r;
        ob[(size_t)c << 10] = acc[pg][ct][r] * inv;
      }
  }
}

// ---------------------------------------------------------------------------
extern "C" void kernel_launch(void* const* d_in, const int* in_sizes, int n_in,
                              void* d_out, int out_size, void* d_ws, size_t ws_size,
                              hipStream_t stream) {
  const float* qf = (const float*)d_in[0];
  const float* kf = (const float*)d_in[1];
  const float* Wq = (const float*)d_in[2];
  const float* bq = (const float*)d_in[3];
  const float* Wk = (const float*)d_in[4];
  const float* bk = (const float*)d_in[5];
  // d_in[6] = vis_CA (unused)
  const int* flag = (const int*)d_in[7];  // same_WqWk
  float* out = (float*)d_out;

  char* ws = (char*)d_ws;
  bf16* Wbh = (bf16*)ws;                    // 64 KiB: [2][64][256] bf16
  bf16* Wbl = (bf16*)(ws + 65536);          // 64 KiB
  bf16* KV = (bf16*)(ws + (1u << 20));      // 20 MiB: [32][8] x 81920B chunks

  vprep_kernel<<<4128, 256, 0, stream>>>(kf, Wq, Wk, flag, KV, Wbh, Wbl);
  proj_kernel<<<dim3(8, 32), 256, 0, stream>>>(Wbh, Wbl, bq, bk, flag, KV);
  attn_kernel<<<512, 256, 0, stream>>>(KV, qf, Wbh, Wbl, bq, out);
}

// Round 15
// 69.803 us; speedup vs baseline: 1.0927x; 1.0927x over previous
//
#include <hip/hip_runtime.h>

typedef __bf16 bf16;
typedef __attribute__((ext_vector_type(4))) __bf16 bf16x4;
typedef __attribute__((ext_vector_type(8))) __bf16 bf16x8;
typedef __attribute__((ext_vector_type(4))) float f32x4;
typedef unsigned int u32;

#define MFMA16(a, b, c) __builtin_amdgcn_mfma_f32_16x16x32_bf16((a), (b), (c), 0, 0, 0)
#define LOG2E 1.4426950408889634f
#define AS1 __attribute__((address_space(1)))
#define AS3 __attribute__((address_space(3)))
#define GLL16(g, l) __builtin_amdgcn_global_load_lds((const AS1 u32*)(g), (AS3 u32*)(l), 16, 0, 0)

// KV chunk, per (b, kt=0..7): 81920 bytes =
//  [0,16384):     K tile [128 q][64 o] bf16, identity rows, 16B-blk swz ^(q&7)
//  [16384,81920): V packed for DIRECT wave-fragment loads: octet (c, mm)
//     (mm = kv>>3 within chunk) at byte 16384 + (c>>6)<<14 + (mm>>2)<<12 +
//     ((c>>4)&3)<<10 + (mm&3)<<8 + (c&15)<<4.  attn wave w: load k=4kb+ct at
//     (w<<14)+(k<<10)+(lane<<4) == A-frag (c=64w+16ct+l16, octet mm=4kb+u).

// ---------------------------------------------------------------------------
// Kernel 1: fused V-pack + W prep (R12 verbatim).
// ---------------------------------------------------------------------------
__global__ __launch_bounds__(256) void vprep_kernel(const float* __restrict__ kf,
                                                    const float* __restrict__ Wq,
                                                    const float* __restrict__ Wk,
                                                    const int* __restrict__ flag,
                                                    bf16* __restrict__ KV,
                                                    bf16* __restrict__ Wbh,
                                                    bf16* __restrict__ Wbl) {
  const int bid = blockIdx.x, t = threadIdx.x;
  if (bid < 4096) {
    int i = (bid << 8) + t;  // (b, c, q8)
    int q8 = i & 127, c = (i >> 7) & 255, b = i >> 15;
    const float* src = kf + ((size_t)(((b << 8) + c)) << 10) + (q8 << 3);
    float4 f0 = *(const float4*)src;
    float4 f1 = *(const float4*)(src + 4);
    bf16x8 v;
    v[0] = (bf16)f0.x; v[1] = (bf16)f0.y; v[2] = (bf16)f0.z; v[3] = (bf16)f0.w;
    v[4] = (bf16)f1.x; v[5] = (bf16)f1.y; v[6] = (bf16)f1.z; v[7] = (bf16)f1.w;
    int kt = q8 >> 4, mm = q8 & 15;
    char* dst = (char*)KV + (size_t)((b << 3) + kt) * 81920 + 16384 +
                ((c >> 6) << 14) + ((mm >> 2) << 12) + (((c >> 4) & 3) << 10) +
                ((mm & 3) << 8) + ((c & 15) << 4);
    *(bf16x8*)dst = v;
  } else {
    int bx = bid - 4096;  // 0..31
    int z = bx >> 4;
    const float* src = (z == 0) ? Wq : ((flag[0] != 0) ? Wq : Wk);
    const float sc = (z == 0) ? LOG2E : 1.0f;  // exp2-domain softmax
    int i = ((((bx & 15) << 8) + t) << 2);
    float4 vv = *(const float4*)(src + i);
    vv.x *= sc; vv.y *= sc; vv.z *= sc; vv.w *= sc;
    bf16x4 hi, lo;
    hi[0] = (bf16)vv.x; lo[0] = (bf16)(vv.x - (float)hi[0]);
    hi[1] = (bf16)vv.y; lo[1] = (bf16)(vv.y - (float)hi[1]);
    hi[2] = (bf16)vv.z; lo[2] = (bf16)(vv.z - (float)hi[2]);
    hi[3] = (bf16)vv.w; lo[3] = (bf16)(vv.w - (float)hi[3]);
    *(bf16x4*)(Wbh + (z << 14) + i) = hi;
    *(bf16x4*)(Wbl + (z << 14) + i) = lo;
  }
}

// ---------------------------------------------------------------------------
// Kernel 2: MFMA projection (R12 verbatim). z=0 -> Qp (log2e-scaled, reads qf
// fp32); z=1 -> KV K-part. z=1 B-frags read bf16 from packed KV V-region.
// ---------------------------------------------------------------------------
__global__ __launch_bounds__(256) void proj_kernel(const float* __restrict__ qf,
                                                   const bf16* __restrict__ Wbh,
                                                   const bf16* __restrict__ Wbl,
                                                   const float* __restrict__ bq,
                                                   const float* __restrict__ bk,
                                                   const int* __restrict__ flag,
                                                   bf16* __restrict__ Qp,
                                                   bf16* __restrict__ KV) {
  const int b = blockIdx.y, z = blockIdx.z;
  const bf16* Wh = Wbh + z * 16384;
  const bf16* Wl = Wbl + z * 16384;
  const float* bias = z ? (flag[0] ? bq : bk) : bq;

  const int t = threadIdx.x;
  const int w = t >> 6, lane = t & 63;
  const int g = lane >> 4, l16 = lane & 15;
  const int wo = w >> 1, wp = w & 1;
  const int o0 = wo << 5;
  const int pbase = (blockIdx.x << 7) + (wp << 6);

  f32x4 acc[2][4];
#pragma unroll
  for (int ot = 0; ot < 2; ++ot) {
    float4 bv = *(const float4*)(bias + o0 + (ot << 4) + (g << 2));
    if (z == 0) { bv.x *= LOG2E; bv.y *= LOG2E; bv.z *= LOG2E; bv.w *= LOG2E; }
#pragma unroll
    for (int pt = 0; pt < 4; ++pt) acc[ot][pt] = (f32x4){bv.x, bv.y, bv.z, bv.w};
  }

  const float* xb = qf + ((((b << 8) + (g << 3)) << 10) + pbase + l16);
  const bf16* whb = Wh + ((o0 + l16) << 8) + (g << 3);
  const bf16* wlb = Wl + ((o0 + l16) << 8) + (g << 3);

  for (int kk = 0; kk < 8; ++kk) {
    bf16x8 ah[2], al[2];
#pragma unroll
    for (int ot = 0; ot < 2; ++ot) {
      ah[ot] = *(const bf16x8*)(whb + (ot << 12) + (kk << 5));
      al[ot] = *(const bf16x8*)(wlb + (ot << 12) + (kk << 5));
    }
#pragma unroll
    for (int pt = 0; pt < 4; ++pt) {
      bf16x8 xf;
      if (z == 0) {
        const float* xk = xb + (kk << 15);
        float xv[8];
#pragma unroll
        for (int j = 0; j < 8; ++j) xv[j] = xk[(j << 10) + (pt << 4)];
#pragma unroll
        for (int j = 0; j < 8; ++j) xf[j] = (bf16)xv[j];
      } else {
        // c = kk*32+8g+j ; p = pbase+16pt+l16 ; kt = p>>7, q'=p&127
        const int p = pbase + (pt << 4) + l16;
        const int mm = (p & 127) >> 3, e = p & 7;
        const char* vp = (const char*)KV + (size_t)((b << 3) + (p >> 7)) * 81920 +
                         16384 + ((kk >> 1) << 14) + ((mm >> 2) << 12) +
                         ((((kk & 1) << 1) + (g >> 1)) << 10) + ((mm & 3) << 8) +
                         (((g & 1) << 3) << 4) + (e << 1);
#pragma unroll
        for (int j = 0; j < 8; ++j)
          xf[j] = *(const bf16*)(vp + (j << 4));
      }
#pragma unroll
      for (int ot = 0; ot < 2; ++ot) {
        acc[ot][pt] = MFMA16(ah[ot], xf, acc[ot][pt]);
        acc[ot][pt] = MFMA16(al[ot], xf, acc[ot][pt]);
      }
    }
  }

#pragma unroll
  for (int ot = 0; ot < 2; ++ot)
#pragma unroll
    for (int pt = 0; pt < 4; ++pt) {
      bf16x4 q4;
#pragma unroll
      for (int r = 0; r < 4; ++r) q4[r] = (bf16)acc[ot][pt][r];
      int p = pbase + (pt << 4) + l16;
      if (z == 0) {
        *(bf16x4*)(Qp + ((((b << 10) + p)) << 6) + o0 + (ot << 4) + (g << 2)) = q4;
      } else {
        int kt = p >> 7, q = p & 127;
        int blk = (o0 >> 3) + (ot << 1) + (g >> 1);
        char* dst = (char*)KV + (size_t)((b << 3) + kt) * 81920 + q * 128 +
                    16 * (blk ^ (q & 7)) + ((g & 1) << 3);
        *(bf16x4*)dst = q4;
      }
    }
}

// ---------------------------------------------------------------------------
// Kernel 3: fused flash attention (R12 + P double-buffer -> SINGLE barrier
// per iter). grid 512 (XCD-swz) x 256 thr. KVBLK=128, 8 iters, no-max exp2
// softmax, V global->VGPR packed frags. Safety: gll K_{t+1} at iter-t top is
// ordered after bar(t-1) (last sK[(t+1)%2] readers were S-phase of t-1);
// P-writes of t+2 into sP[t%2] are ordered after bar(t+1) which implies all
// PV(t) readers finished. Lagging PV overlaps leading waves' loads/S.
// ---------------------------------------------------------------------------
__global__ __launch_bounds__(256, 2) void attn_kernel(const bf16* __restrict__ KV,
                                                      const bf16* __restrict__ Qp,
                                                      float* __restrict__ out) {
  const int bid = blockIdx.x;
  const int wkid = ((bid & 7) << 6) + (bid >> 3);  // bijective: 512 % 8 == 0
  const int b = wkid >> 4, ptile = wkid & 15;
  const int p0 = ptile << 6;
  const int t = threadIdx.x;
  const int w = t >> 6, lane = t & 63;
  const int u = lane >> 4, l16 = lane & 15;

  __shared__ __align__(16) unsigned char sK[2][16384];  // K dbuf (gll target)
  __shared__ __align__(16) unsigned char sP[2][16384];  // P dbuf [64px][128kv]
  __shared__ float sL[64];

  // Q B-fragments for this wave's 16 px (col=px, k=o)
  const bf16* qb = Qp + (((size_t)((b << 10) + p0 + (w << 4) + l16)) << 6) + (u << 3);
  const bf16x8 qa0 = *(const bf16x8*)qb;
  const bf16x8 qa1 = *(const bf16x8*)(qb + 32);

  const char* chunk0 = (const char*)KV + (size_t)b * (8 * 81920);
  const int Rb = ((l16 >> 2) << 3) + ((l16 & 3) << 1);  // K row perm base

  f32x4 acc[4][4];  // [pg][ct]: c = 64w + 16ct + 4u + r ; px = 16pg + l16
#pragma unroll
  for (int i = 0; i < 4; ++i)
#pragma unroll
    for (int j = 0; j < 4; ++j) acc[i][j] = (f32x4){0.f, 0.f, 0.f, 0.f};
  float l_ = 0.f;

  const int prow = (w << 4) + l16, pswz = prow & 7;

  // ---- prologue: stage K_0 (4 gll/wave) ----
  {
    const char* g = chunk0 + (w << 12) + (lane << 4);
    unsigned char* l = sK[0] + (w << 12);
#pragma unroll
    for (int op = 0; op < 4; ++op) GLL16(g + op * 1024, l + op * 1024);
  }
  asm volatile("s_waitcnt vmcnt(0)" ::: "memory");
  __syncthreads();

  for (int kt = 0; kt < 8; ++kt) {
    const int cur = kt & 1;
    // ---- K_{t+1} gll into other buffer (safe: S-readers of that buffer
    //      finished before bar(t-1), which precedes this in program order) ----
    if (kt < 7) {
      const char* g = chunk0 + (kt + 1) * 81920 + (w << 12) + (lane << 4);
      unsigned char* l = sK[cur ^ 1] + (w << 12);
#pragma unroll
      for (int op = 0; op < 4; ++op) GLL16(g + op * 1024, l + op * 1024);
    }
    // ---- V_t -> regs: 16 coalesced 1KB loads (packed A-fragments) ----
    bf16x8 vr[16];  // vr[4kb+ct] = V A-frag (c=64w+16ct+l16, octet 4kb+u)
    const char* vsrc = chunk0 + kt * 81920 + 16384 + (w << 14) + (lane << 4);
#pragma unroll
    for (int k = 0; k < 16; ++k) vr[k] = *(const bf16x8*)(vsrc + (k << 10));
    const unsigned char* sKc = sK[cur];

    // ---- S^T = K·Q^T (16 mfma, permuted K rows from swizzled LDS) ----
    f32x4 s[8];
#pragma unroll
    for (int qt = 0; qt < 8; ++qt) {
      const int R = Rb + (qt & 1) + ((qt >> 1) << 5);
      const int rb = R * 128;
      bf16x8 k0 = *(const bf16x8*)(sKc + rb + 16 * (u ^ (R & 7)));
      bf16x8 k1 = *(const bf16x8*)(sKc + rb + 16 * ((u + 4) ^ (R & 7)));
      f32x4 z = (f32x4){0.f, 0.f, 0.f, 0.f};
      z = MFMA16(k0, qa0, z);
      s[qt] = MFMA16(k1, qa1, z);
    }
    // ---- NO-MAX softmax: P = exp2(S); l += sum ----
#pragma unroll
    for (int qt = 0; qt < 8; ++qt)
#pragma unroll
      for (int r = 0; r < 4; ++r) s[qt][r] = exp2f(s[qt][r]);
    float rs = 0.f;
#pragma unroll
    for (int qt = 0; qt < 8; ++qt)
      rs += (s[qt][0] + s[qt][1]) + (s[qt][2] + s[qt][3]);
    rs += __shfl_xor(rs, 16);
    rs += __shfl_xor(rs, 32);
    l_ += rs;
    // ---- P -> bf16 octets (in-lane), publish 4 b128 into sP[cur] ----
#pragma unroll
    for (int a = 0; a < 4; ++a) {
      bf16x8 pb;
#pragma unroll
      for (int r = 0; r < 4; ++r) {
        pb[2 * r] = (bf16)s[2 * a][r];
        pb[2 * r + 1] = (bf16)s[2 * a + 1][r];
      }
      *(bf16x8*)(sP[cur] + prow * 256 + 16 * (((a << 2) + u) ^ pswz)) = pb;
    }
    asm volatile("s_waitcnt vmcnt(0)" ::: "memory");  // K_{t+1} + vr landed
    __syncthreads();  // SINGLE barrier: P visible, K ready, S-reads done

    // ---- PV: 4 kb-groups x [4 P-frag reads + 16 mfma] (reads sP[cur]) ----
#pragma unroll
    for (int kb = 0; kb < 4; ++kb) {
      bf16x8 pbr[4];
#pragma unroll
      for (int pg = 0; pg < 4; ++pg) {
        const int rr = (pg << 4) + l16;
        pbr[pg] = *(const bf16x8*)(sP[cur] + rr * 256 + 16 * (((kb << 2) + u) ^ (rr & 7)));
      }
#pragma unroll
      for (int ct = 0; ct < 4; ++ct)
#pragma unroll
        for (int pg = 0; pg < 4; ++pg)
          acc[pg][ct] = MFMA16(vr[(kb << 2) + ct], pbr[pg], acc[pg][ct]);
    }
  }

  // ---- epilogue: share l, per-lane normalize, direct stores ----
  __syncthreads();  // PV(7) sP reads done block-wide before sL reuse pattern
  if (lane < 16) sL[(w << 4) + lane] = l_;
  __syncthreads();
#pragma unroll
  for (int pg = 0; pg < 4; ++pg) {
    const float inv = 1.f / sL[(pg << 4) + l16];
    float* ob = out + ((size_t)b << 18) + p0 + (pg << 4) + l16;
#pragma unroll
    for (int ct = 0; ct < 4; ++ct)
#pragma unroll
      for (int r = 0; r < 4; ++r) {
        int c = (w << 6) + (ct << 4) + (u << 2) + r;
        ob[(size_t)c << 10] = acc[pg][ct][r] * inv;
      }
  }
}

// ---------------------------------------------------------------------------
extern "C" void kernel_launch(void* const* d_in, const int* in_sizes, int n_in,
                              void* d_out, int out_size, void* d_ws, size_t ws_size,
                              hipStream_t stream) {
  const float* qf = (const float*)d_in[0];
  const float* kf = (const float*)d_in[1];
  const float* Wq = (const float*)d_in[2];
  const float* bq = (const float*)d_in[3];
  const float* Wk = (const float*)d_in[4];
  const float* bk = (const float*)d_in[5];
  // d_in[6] = vis_CA (unused)
  const int* flag = (const int*)d_in[7];  // same_WqWk
  float* out = (float*)d_out;

  char* ws = (char*)d_ws;
  bf16* Qp = (bf16*)ws;                          // 4 MiB: [32][1024][64] bf16
  bf16* Wbh = (bf16*)(ws + (4u << 20));          // 64 KiB
  bf16* Wbl = (bf16*)(ws + (4u << 20) + 65536);  // 64 KiB
  bf16* KV = (bf16*)(ws + (5u << 20));           // 20 MiB: [32][8] x 81920B chunks

  vprep_kernel<<<4128, 256, 0, stream>>>(kf, Wq, Wk, flag, KV, Wbh, Wbl);
  proj_kernel<<<dim3(8, 32, 2), 256, 0, stream>>>(qf, Wbh, Wbl, bq, bk, flag, Qp, KV);
  attn_kernel<<<512, 256, 0, stream>>>(KV, Qp, out);
}